// Round 11
// baseline (84.471 us; speedup 1.0000x reference)
//
#include <hip/hip_runtime.h>
#include <float.h>

// E=4, L=8, S=512, F=32, G=512. KDE = linear-binned histogram + Gaussian conv.
// R11: phase-decoupled pipeline — per-(lf,e) hist blocks for latency overlap.

#if __has_builtin(__builtin_amdgcn_exp2f)
__device__ __forceinline__ float fast_exp2(float x) { return __builtin_amdgcn_exp2f(x); }
#else
__device__ __forceinline__ float fast_exp2(float x) { return exp2f(x); }
#endif

#define MAXR 150     // max conv radius (bins); runtime R = ceil(3.5/h) ~ 67
#define PADL 160     // zero padding each side of the 513 hist bins
#define HW   840     // hist row width: PADL + 513 + PADR (multiple of 4)
#define WOFF 163     // center of symmetric weight table (=> aligned float4 chunks)
#define WFULL 336    // weight table floats (84 float4)

// ---- workspace layout (float offsets) ----
#define PT_OFF    0        // proj^T [E][L][F][S] = 524288 floats (unscaled)
#define SX_OFF    524288   // [256 blk][32 f] sum(x)
#define SXX_OFF   532480   // [256 blk][32 f] sum(x^2)
#define MIN_OFF   540672   // [256] per-block min
#define MAX_OFF   540928   // [256] per-block max
#define CNT_OFF   541184   // completion counter (int)
#define CSH_OFF   541200   // [8] consts: h, A, B, scale, R
#define FINE_OFF  541216   // [256 lf][4 e][512] conv results = 524288 floats

// ---------- K1: proj^T + std partials + min/max (known-good, absmax 0.0) ----------
__global__ __launch_bounds__(256) void stage_prep(const float* __restrict__ matrix,
                                                  const float* __restrict__ params,
                                                  float* __restrict__ PT,
                                                  float* __restrict__ sxg,
                                                  float* __restrict__ sxxg,
                                                  float* __restrict__ minp,
                                                  float* __restrict__ maxp,
                                                  int* __restrict__ counter) {
    __shared__ float M[64][33];    // +1 pad: proj pass reads column-wise
    __shared__ float Pm[32][32];
    __shared__ float sxr[8][32], sxxr[8][32];
    __shared__ float rmin[4], rmax[4];
    const int bid = blockIdx.x;        // (e*8+l)*8 + stile
    const int s0 = (bid & 7) << 6;
    const int el = bid >> 3;
    const int t = threadIdx.x;
    if (bid == 0 && t == 0) *counter = 0;   // reset for stage_reduce's last-block
    {
        const float4 v = reinterpret_cast<const float4*>(params)[t];
        const int base = t << 2;
        Pm[base >> 5][base & 31]       = v.x;
        Pm[base >> 5][(base & 31) + 1] = v.y;
        Pm[base >> 5][(base & 31) + 2] = v.z;
        Pm[base >> 5][(base & 31) + 3] = v.w;
    }
    const float4* mb4 = reinterpret_cast<const float4*>(matrix + (size_t)(el * 512 + s0) * 32);
    #pragma unroll
    for (int k = t; k < 512; k += 256) {
        const float4 v = mb4[k];
        const int base = k << 2;
        M[base >> 5][base & 31]       = v.x;
        M[base >> 5][(base & 31) + 1] = v.y;
        M[base >> 5][(base & 31) + 2] = v.z;
        M[base >> 5][(base & 31) + 3] = v.w;
    }
    __syncthreads();
    {
        const int f = t & 31, r = t >> 5;
        float sx = 0.f, sxx = 0.f;
        #pragma unroll
        for (int k = 0; k < 8; ++k) {
            float v = M[r * 8 + k][f];
            sx += v; sxx += v * v;
        }
        sxr[r][f] = sx; sxxr[r][f] = sxx;
    }
    const int s = t & 63;
    const int g0 = t >> 6;
    float lmin = FLT_MAX, lmax = -FLT_MAX;
    #pragma unroll
    for (int pass = 0; pass < 8; ++pass) {
        const int g = (pass << 2) + g0;
        float acc = 0.f;
        #pragma unroll
        for (int fp = 0; fp < 32; ++fp) acc += M[s][fp] * Pm[fp][g];
        lmin = fminf(lmin, acc);
        lmax = fmaxf(lmax, acc);
        PT[(size_t)(el * 32 + g) * 512 + s0 + s] = acc;
    }
    #pragma unroll
    for (int off = 32; off >= 1; off >>= 1) {
        lmin = fminf(lmin, __shfl_xor(lmin, off, 64));
        lmax = fmaxf(lmax, __shfl_xor(lmax, off, 64));
    }
    if ((t & 63) == 0) { rmin[t >> 6] = lmin; rmax[t >> 6] = lmax; }
    __syncthreads();
    if (t < 32) {
        float a = 0.f, b = 0.f;
        #pragma unroll
        for (int r = 0; r < 8; ++r) { a += sxr[r][t]; b += sxxr[r][t]; }
        sxg[bid * 32 + t] = a;
        sxxg[bid * 32 + t] = b;
    }
    if (t == 0) {
        minp[bid] = fminf(fminf(rmin[0], rmin[1]), fminf(rmin[2], rmin[3]));
        maxp[bid] = fmaxf(fmaxf(rmax[0], rmax[1]), fmaxf(rmax[2], rmax[3]));
    }
}

// ---------- K2: single-block consts finalize ----------
__global__ __launch_bounds__(1024) void stage_consts(const float* __restrict__ sxg,
                                                     const float* __restrict__ sxxg,
                                                     const float* __restrict__ minp,
                                                     const float* __restrict__ maxp,
                                                     float* __restrict__ csh_g) {
    __shared__ float wsum[16], wmn[16], wmx[16];
    const int t = threadIdx.x;
    float sf;
    {   // one (e,l,f) triple per thread
        const int el = t >> 5, fc = t & 31;
        const int base = el * 256 + fc;
        float Sx = 0.f, Sxx = 0.f;
        #pragma unroll
        for (int tile = 0; tile < 8; ++tile) { Sx += sxg[base + tile * 32]; Sxx += sxxg[base + tile * 32]; }
        const float mean = Sx * (1.0f / 512.0f);
        const float var = (Sxx - Sx * mean) * (1.0f / 511.0f);   // ddof=1
        sf = sqrtf(fmaxf(var, 0.f));
    }
    float mn = (t < 256) ? minp[t] : FLT_MAX;
    float mx = (t < 256) ? maxp[t] : -FLT_MAX;
    #pragma unroll
    for (int off = 32; off >= 1; off >>= 1) {
        sf += __shfl_xor(sf, off, 64);
        mn = fminf(mn, __shfl_xor(mn, off, 64));
        mx = fmaxf(mx, __shfl_xor(mx, off, 64));
    }
    if ((t & 63) == 0) { wsum[t >> 6] = sf; wmn[t >> 6] = mn; wmx[t >> 6] = mx; }
    __syncthreads();
    if (t == 0) {
        float s = 0.f, lo = FLT_MAX, hi = -FLT_MAX;
        #pragma unroll
        for (int w = 0; w < 16; ++w) {
            s += wsum[w]; lo = fminf(lo, wmn[w]); hi = fmaxf(hi, wmx[w]);
        }
        const float stdv = s * (1.0f / 1024.0f);
        const float left  = lo / stdv;
        const float right = hi / stdv;
        const float bw = 1.06f * 0.28717458874925877f;     // mean(std(m)) == 1
        const float delta = (right - left) * (1.0f / 512.0f);
        const float gstep = (right - left) * (1.0f / 511.0f);
        const float divisor = 2.5066282746310002f * bw;
        const float cpos = (0.5f / (bw * bw)) * 1.4426950408889634f;
        const float kf = sqrtf(cpos);              // kernel = exp2(-((x-p)*kf)^2)
        const float h = gstep * kf;                // grid step, scaled units
        const float invh = 1.0f / h;
        csh_g[0] = h;
        csh_g[1] = (1.0f / stdv) * kf * invh;      // A: bin = raw*A - B
        csh_g[2] = left * kf * invh;               // B
        csh_g[3] = delta * 0.5f / divisor;         // final scale
        csh_g[4] = (float)min((int)(3.5f / h) + 1, MAXR);   // R
    }
}

// ---------- K3: per-(lf,e) splat + conv ----------
// 1024 blocks = lf*4 + e; 256 threads.
__global__ __launch_bounds__(256) void stage_hist(const float* __restrict__ PT,
                                                  const float* __restrict__ csh_g,
                                                  const int* __restrict__ dlen,
                                                  float* __restrict__ fine_g) {
    __shared__ __align__(16) int   histI[HW];     // fixed-point bins -> punned float
    __shared__ __align__(16) float wfull[WFULL];  // symmetric weights, zero-padded
    const int t = threadIdx.x;
    const int bid = blockIdx.x;
    const int e = bid & 3, lf = bid >> 2;
    const int l = lf >> 5, f = lf & 31;

    const float h = csh_g[0], A = csh_g[1], B = csh_g[2];
    const int R = (int)csh_g[4];
    const int lenE = dlen[(e << 3) + l];

    // zero hist + weight table (the only exps)
    #pragma unroll
    for (int k = t; k < HW; k += 256) histI[k] = 0;
    #pragma unroll
    for (int k = t; k < WFULL; k += 256) {
        const int d = k - WOFF;
        const int ad = (d < 0) ? -d : d;
        const float u = (float)ad * h;
        wfull[k] = (ad <= R) ? fast_exp2(-(u * u)) : 0.f;
    }
    __syncthreads();

    // linear splat: 2 samples per thread
    {
        const size_t row = ((size_t)(((e << 3) + l) * 32 + f) << 9);
        const float2 xv = *reinterpret_cast<const float2*>(&PT[row + (t << 1)]);
        const float u0 = fmaf(xv.x, A, -B);
        const float u1 = fmaf(xv.y, A, -B);
        const float uu[2] = { u0, u1 };
        #pragma unroll
        for (int q = 0; q < 2; ++q) {
            if ((t << 1) + q < lenE) {
                const float u = fminf(fmaxf(uu[q], 0.f), 511.f);
                const int   b = (int)u;
                const float fr = u - (float)b;
                const int w1 = (int)(fr * 16384.f + 0.5f);
                atomicAdd(&histI[PADL + b], 16384 - w1);
                atomicAdd(&histI[PADL + b + 1], w1);
            }
        }
    }
    __syncthreads();

    // convert bins to float in place, folding 1/(16384*len)
    {
        const float ce = (1.0f / 16384.0f) / (float)lenE;
        #pragma unroll
        for (int k = t; k < HW; k += 256) {
            const int iv = histI[k];
            *reinterpret_cast<float*>(&histI[k]) = (float)iv * ce;   // same-thread RW
        }
    }
    __syncthreads();

    // vectorized conv: threads 0..127, 4 adjacent fine points each
    if (t < 128) {
        const float4* __restrict__ hf4 = reinterpret_cast<const float4*>(&histI[0]);
        const float4* __restrict__ wf4 = reinterpret_cast<const float4*>(&wfull[0]);
        const int hbase = 40 + t;              // (PADL + 4t)/4
        const int i_lo = -((R + 3) >> 2) - 1;
        const int i_hi = (R + 3) >> 2;
        float o0 = 0.f, o1 = 0.f, o2 = 0.f, o3 = 0.f;
        float4 W0 = wf4[40 + i_lo];
        for (int i = i_lo; i <= i_hi; ++i) {
            const float4 W1 = wf4[41 + i];
            const float4 H = hf4[hbase + i];
            o0 += H.x * W0.w + H.y * W1.x + H.z * W1.y + H.w * W1.z;
            o1 += H.x * W0.z + H.y * W0.w + H.z * W1.x + H.w * W1.y;
            o2 += H.x * W0.y + H.y * W0.z + H.z * W0.w + H.w * W1.x;
            o3 += H.x * W0.x + H.y * W0.y + H.z * W0.z + H.w * W0.w;
            W0 = W1;
        }
        *reinterpret_cast<float4*>(&fine_g[((size_t)bid << 9) + (t << 2)]) =
            make_float4(o0, o1, o2, o3);
    }
}

// ---------- K4: pair L1 reduction + outputs ----------
// 256 blocks = one per (l,f); 512 threads = one fine point each.
__global__ __launch_bounds__(512) void stage_reduce(const float* __restrict__ fine_g,
                                                    const float* __restrict__ csh_g,
                                                    int* __restrict__ counter,
                                                    float* __restrict__ out) {
    __shared__ float wred[8][6];
    __shared__ int lastf;
    const int t = threadIdx.x;
    const int lf = blockIdx.x;
    const size_t base4 = (size_t)(lf << 2) << 9;
    const float r0 = fine_g[base4 + t];
    const float r1 = fine_g[base4 + 512 + t];
    const float r2 = fine_g[base4 + 1024 + t];
    const float r3 = fine_g[base4 + 1536 + t];
    float pr[6];
    pr[0] = fabsf(r0 - r1);
    pr[1] = fabsf(r0 - r2);
    pr[2] = fabsf(r0 - r3);
    pr[3] = fabsf(r1 - r2);
    pr[4] = fabsf(r1 - r3);
    pr[5] = fabsf(r2 - r3);
    #pragma unroll
    for (int pi = 0; pi < 6; ++pi) {
        float v = pr[pi];
        #pragma unroll
        for (int off = 32; off >= 1; off >>= 1) v += __shfl_xor(v, off, 64);
        if ((t & 63) == 0) wred[t >> 6][pi] = v;
    }
    __syncthreads();
    if (t == 0) {
        const float scale = csh_g[3];
        float v[6];
        #pragma unroll
        for (int pi = 0; pi < 6; ++pi) {
            float sm = 0.f;
            #pragma unroll
            for (int w = 0; w < 8; ++w) sm += wred[w][pi];
            v[pi] = sm * scale;
        }
        float testv = v[0];
        #pragma unroll
        for (int pi = 1; pi < 6; ++pi) testv = fmaxf(testv, v[pi]);
        const float trainv = fmaxf(fmaxf(v[0], v[1]), v[3]);  // pairs (0,1),(0,2),(1,2)
        out[lf] = trainv;
        out[256 + lf] = testv;
        __threadfence();
        const int old = __hip_atomic_fetch_add(counter, 1, __ATOMIC_ACQ_REL,
                                               __HIP_MEMORY_SCOPE_AGENT);
        lastf = (old == 255);
    }
    __syncthreads();
    if (lastf && t < 64) {
        const int ff = t & 31;
        const int base = (t >= 32) ? 256 : 0;      // lanes 0-31: train, 32-63: test
        float m = -FLT_MAX;
        #pragma unroll
        for (int ll = 0; ll < 8; ++ll) {
            const float val = __hip_atomic_load(&out[base + ll * 32 + ff],
                                                __ATOMIC_RELAXED, __HIP_MEMORY_SCOPE_AGENT);
            m = fmaxf(m, val);
        }
        #pragma unroll
        for (int off = 16; off >= 1; off >>= 1) m += __shfl_xor(m, off, 32);
        if (ff == 0) out[512 + (base ? 1 : 0)] = m * (1.0f / 32.0f);
    }
}

extern "C" void kernel_launch(void* const* d_in, const int* in_sizes, int n_in,
                              void* d_out, int out_size, void* d_ws, size_t ws_size,
                              hipStream_t stream) {
    (void)in_sizes; (void)n_in; (void)out_size; (void)ws_size;
    const float* matrix = (const float*)d_in[0];
    const float* params = (const float*)d_in[1];
    const int*   dlen   = (const int*)d_in[2];
    float* out = (float*)d_out;
    float* ws  = (float*)d_ws;
    float* PT   = ws + PT_OFF;
    float* sxg  = ws + SX_OFF;
    float* sxxg = ws + SXX_OFF;
    float* minp = ws + MIN_OFF;
    float* maxp = ws + MAX_OFF;
    int*   cnt  = (int*)(ws + CNT_OFF);
    float* cshg = ws + CSH_OFF;
    float* fine = ws + FINE_OFF;

    hipLaunchKernelGGL(stage_prep,   dim3(256),  dim3(256),  0, stream,
                       matrix, params, PT, sxg, sxxg, minp, maxp, cnt);
    hipLaunchKernelGGL(stage_consts, dim3(1),    dim3(1024), 0, stream,
                       sxg, sxxg, minp, maxp, cshg);
    hipLaunchKernelGGL(stage_hist,   dim3(1024), dim3(256),  0, stream,
                       PT, cshg, dlen, fine);
    hipLaunchKernelGGL(stage_reduce, dim3(256),  dim3(512),  0, stream,
                       fine, cshg, cnt, out);
}

// Round 12
// 84.204 us; speedup vs baseline: 1.0032x; 1.0032x over previous
//
#include <hip/hip_runtime.h>
#include <float.h>

// E=4, L=8, S=512, F=32, G=512. KDE = linear-binned histogram (float LDS
// atomics) + Gaussian conv at stride-2 coarse bins + cubic interp (R8-verified
// weights). Weight-table exps only (~140/block).

#if __has_builtin(__builtin_amdgcn_exp2f)
__device__ __forceinline__ float fast_exp2(float x) { return __builtin_amdgcn_exp2f(x); }
#else
__device__ __forceinline__ float fast_exp2(float x) { return exp2f(x); }
#endif

#define MAXR 150     // max conv radius (bins); runtime R = ceil(3.5/h) ~ 67
#define PADL 160     // zero padding each side of the 513 hist bins
#define HW   840     // hist row width: PADL + 513 + PADR (multiple of 4)
#define WOFF 163     // center of symmetric weight table
#define WFULL 336    // weight table floats (84 float4)

// ---- workspace layout (float offsets) ----
#define PT_OFF    0        // proj^T [E][L][F][S] = 524288 floats (unscaled)
#define SX_OFF    524288   // [256 blk][32 f] sum(x)
#define SXX_OFF   532480   // [256 blk][32 f] sum(x^2)
#define MIN_OFF   540672   // [256] per-block min
#define MAX_OFF   540928   // [256] per-block max
#define CNT_OFF   541184   // completion counter (int)

// ---------- K1: proj^T + std partials + min/max (register-row matmul) ----------
__global__ __launch_bounds__(256) void stage_prep(const float* __restrict__ matrix,
                                                  const float* __restrict__ params,
                                                  float* __restrict__ PT,
                                                  float* __restrict__ sxg,
                                                  float* __restrict__ sxxg,
                                                  float* __restrict__ minp,
                                                  float* __restrict__ maxp,
                                                  int* __restrict__ counter) {
    __shared__ float Pm[1024];         // params [fp][g] row-major
    __shared__ float sxr[8][32], sxxr[8][32];
    __shared__ float rmin[4], rmax[4];
    const int bid = blockIdx.x;        // el*8 + stile
    const int s0 = (bid & 7) << 6;
    const int el = bid >> 3;
    const int t = threadIdx.x;
    if (bid == 0 && t == 0) *counter = 0;   // reset for K2's last-block trick
    reinterpret_cast<float4*>(Pm)[t] = reinterpret_cast<const float4*>(params)[t];
    // std partials straight from global (coalesced: f = lane low bits)
    {
        const int f = t & 31, r = t >> 5;
        const float* mb = matrix + (size_t)(el * 512 + s0) * 32;
        float sx = 0.f, sxx = 0.f;
        #pragma unroll
        for (int k = 0; k < 8; ++k) {
            const float v = mb[(r * 8 + k) * 32 + f];
            sx += v; sxx += v * v;
        }
        sxr[r][f] = sx; sxxr[r][f] = sxx;
    }
    __syncthreads();
    // thread (gq = t>>6, sl = t&63): sample row in registers, 8 outputs
    const int gq = t >> 6, sl = t & 63;
    const int s = s0 + sl;
    float row[32];
    {
        const float4* rp = reinterpret_cast<const float4*>(matrix + ((size_t)(el * 512 + s) << 5));
        #pragma unroll
        for (int i = 0; i < 8; ++i) {
            const float4 v = rp[i];
            row[4 * i] = v.x; row[4 * i + 1] = v.y;
            row[4 * i + 2] = v.z; row[4 * i + 3] = v.w;
        }
    }
    float acc[8];
    #pragma unroll
    for (int j = 0; j < 8; ++j) acc[j] = 0.f;
    const float4* pm4 = reinterpret_cast<const float4*>(Pm);
    #pragma unroll
    for (int fp = 0; fp < 32; ++fp) {
        const float4 w0 = pm4[fp * 8 + gq * 2];       // broadcast b128 (gq wave-uniform)
        const float4 w1 = pm4[fp * 8 + gq * 2 + 1];
        const float rv = row[fp];
        acc[0] += rv * w0.x; acc[1] += rv * w0.y;
        acc[2] += rv * w0.z; acc[3] += rv * w0.w;
        acc[4] += rv * w1.x; acc[5] += rv * w1.y;
        acc[6] += rv * w1.z; acc[7] += rv * w1.w;
    }
    float lmin = FLT_MAX, lmax = -FLT_MAX;
    #pragma unroll
    for (int j = 0; j < 8; ++j) {
        PT[(size_t)(el * 32 + gq * 8 + j) * 512 + s] = acc[j];   // coalesced over sl
        lmin = fminf(lmin, acc[j]); lmax = fmaxf(lmax, acc[j]);
    }
    #pragma unroll
    for (int off = 32; off >= 1; off >>= 1) {
        lmin = fminf(lmin, __shfl_xor(lmin, off, 64));
        lmax = fmaxf(lmax, __shfl_xor(lmax, off, 64));
    }
    if ((t & 63) == 0) { rmin[t >> 6] = lmin; rmax[t >> 6] = lmax; }
    __syncthreads();
    if (t < 32) {
        float a = 0.f, b = 0.f;
        #pragma unroll
        for (int r = 0; r < 8; ++r) { a += sxr[r][t]; b += sxxr[r][t]; }
        sxg[bid * 32 + t] = a;
        sxxg[bid * 32 + t] = b;
    }
    if (t == 0) {
        minp[bid] = fminf(fminf(rmin[0], rmin[1]), fminf(rmin[2], rmin[3]));
        maxp[bid] = fmaxf(fmaxf(rmax[0], rmax[1]), fmaxf(rmax[2], rmax[3]));
    }
}

// ---------- K2: consts + float-atomic splat + stride-2 conv + interp + outputs ----------
// 256 blocks = one per (l,f); 512 threads.
__global__ __launch_bounds__(512) void stage_kde4(const float* __restrict__ PT,
                                                  const float* __restrict__ sxg,
                                                  const float* __restrict__ sxxg,
                                                  const float* __restrict__ minp,
                                                  const float* __restrict__ maxp,
                                                  const int* __restrict__ dlen,
                                                  int* __restrict__ counter,
                                                  float* __restrict__ out) {
    __shared__ __align__(16) float histF[4][HW];  // float bins (ds_add_f32 atomics)
    __shared__ __align__(16) float fine[4][512];  // red on fine grid
    __shared__ __align__(16) float wfull[WFULL];  // symmetric weights, zero-padded
    __shared__ float wsum[8], wmn[8], wmx[8];
    __shared__ float wred[8][6];
    __shared__ float csh[8];
    __shared__ int   Rsh;
    __shared__ int   lensh[4];
    __shared__ int   lastf;
    const int t = threadIdx.x;
    const int lf = blockIdx.x;
    const int l = lf >> 5, f = lf & 31;

    if (t < 4) lensh[t] = dlen[(t << 3) + l];
    {   // zero histogram via float4 (pads included)
        float4* hflat = reinterpret_cast<float4*>(&histF[0][0]);
        #pragma unroll
        for (int k = t; k < HW; k += 512) hflat[k] = make_float4(0.f, 0.f, 0.f, 0.f);
    }

    // ---- consts ----
    {
        float sf = 0.f;
        #pragma unroll
        for (int tr = t; tr < 1024; tr += 512) {     // (e,l,f) triples
            const int el = tr >> 5, fc = tr & 31;
            const int base = el * 256 + fc;
            float Sx = 0.f, Sxx = 0.f;
            #pragma unroll
            for (int tile = 0; tile < 8; ++tile) { Sx += sxg[base + tile * 32]; Sxx += sxxg[base + tile * 32]; }
            const float mean = Sx * (1.0f / 512.0f);
            const float var = (Sxx - Sx * mean) * (1.0f / 511.0f);   // ddof=1
            sf += sqrtf(fmaxf(var, 0.f));
        }
        float mn = (t < 256) ? minp[t] : FLT_MAX;
        float mx = (t < 256) ? maxp[t] : -FLT_MAX;
        #pragma unroll
        for (int off = 32; off >= 1; off >>= 1) {
            sf += __shfl_xor(sf, off, 64);
            mn = fminf(mn, __shfl_xor(mn, off, 64));
            mx = fmaxf(mx, __shfl_xor(mx, off, 64));
        }
        if ((t & 63) == 0) { wsum[t >> 6] = sf; wmn[t >> 6] = mn; wmx[t >> 6] = mx; }
        __syncthreads();
        if (t == 0) {
            float s = 0.f, lo = FLT_MAX, hi = -FLT_MAX;
            #pragma unroll
            for (int w = 0; w < 8; ++w) {
                s += wsum[w]; lo = fminf(lo, wmn[w]); hi = fmaxf(hi, wmx[w]);
            }
            const float stdv = s * (1.0f / 1024.0f);
            const float left  = lo / stdv;
            const float right = hi / stdv;
            const float bw = 1.06f * 0.28717458874925877f;     // mean(std(m)) == 1
            const float delta = (right - left) * (1.0f / 512.0f);
            const float gstep = (right - left) * (1.0f / 511.0f);
            const float divisor = 2.5066282746310002f * bw;
            const float cpos = (0.5f / (bw * bw)) * 1.4426950408889634f;
            const float kf = sqrtf(cpos);          // kernel = exp2(-((x-p)*kf)^2)
            const float h = gstep * kf;            // grid step, scaled units
            const float invh = 1.0f / h;
            csh[0] = h;
            csh[1] = (1.0f / stdv) * kf * invh;    // A: bin = raw*A - B
            csh[2] = left * kf * invh;             // B
            csh[3] = delta * 0.5f / divisor;       // final scale
            Rsh = min((int)(3.5f / h) + 1, MAXR);  // truncation tail ~1e-5
        }
    }
    __syncthreads();
    const float h = csh[0], A = csh[1], B = csh[2];
    const int R = Rsh;

    // ---- weight table: the ONLY exps in the kernel ----
    if (t < WFULL) {
        const int d = t - WOFF;
        const int ad = (d < 0) ? -d : d;
        const float u = (float)ad * h;
        wfull[t] = (ad <= R) ? fast_exp2(-(u * u)) : 0.f;
    }

    // ---- linear splat, float atomics, 1/len folded in ----
    const int e = t >> 7;
    {
        const int sbase = (t & 127) << 2;
        const int lenE = lensh[e];
        const float invLen = 1.0f / (float)lenE;
        const size_t row = ((size_t)(((e << 3) + l) * 32 + f) << 9);
        const float4 xv = *reinterpret_cast<const float4*>(&PT[row + sbase]);
        const float uu[4] = { fmaf(xv.x, A, -B), fmaf(xv.y, A, -B),
                              fmaf(xv.z, A, -B), fmaf(xv.w, A, -B) };
        #pragma unroll
        for (int q = 0; q < 4; ++q) {
            if (sbase + q < lenE) {
                const float u = fminf(fmaxf(uu[q], 0.f), 511.f);
                const int   b = (int)u;
                const float fr = u - (float)b;
                atomicAdd(&histF[e][PADL + b], (1.f - fr) * invLen);
                atomicAdd(&histF[e][PADL + b + 1], fr * invLen);
            }
        }
    }
    __syncthreads();

    // ---- stride-2 conv: t<256 -> (e2 = t>>6, tid = t&63), 4 even-bin outputs ----
    if (t < 256) {
        const int e2 = t >> 6, tid = t & 63;
        const float4* __restrict__ hf4 = reinterpret_cast<const float4*>(&histF[e2][0]);
        const float4* __restrict__ wf4 = reinterpret_cast<const float4*>(&wfull[0]);
        const int hb = 40 + 2 * tid;           // (PADL + 8*tid)/4
        const int i_lo = -((R + 6) >> 2);
        const int i_hi = (R + 6) >> 2;
        float o0 = 0.f, o1 = 0.f, o2 = 0.f, o3 = 0.f;
        float4 Wa = wf4[39 + i_lo];
        float4 Wb = wf4[40 + i_lo];
        for (int i = i_lo; i <= i_hi; ++i) {
            const float4 Wc = wf4[41 + i];
            const float4 H = hf4[hb + i];
            // output m at bin 8*tid+2m: weight table idx = WOFF + 4i + j - 2m
            o0 += H.x * Wb.w + H.y * Wc.x + H.z * Wc.y + H.w * Wc.z;   // m=0
            o1 += H.x * Wb.y + H.y * Wb.z + H.z * Wb.w + H.w * Wc.x;   // m=1
            o2 += H.x * Wa.w + H.y * Wb.x + H.z * Wb.y + H.w * Wb.z;   // m=2
            o3 += H.x * Wa.y + H.y * Wa.z + H.z * Wa.w + H.w * Wb.x;   // m=3
            Wa = Wb; Wb = Wc;
        }
        const int gbase = (tid << 3);
        fine[e2][gbase]     = o0;
        fine[e2][gbase + 2] = o1;
        fine[e2][gbase + 4] = o2;
        fine[e2][gbase + 6] = o3;
    }
    __syncthreads();

    // ---- cubic interp to odd fine points (R8-verified weights) ----
    #pragma unroll
    for (int it = 0; it < 2; ++it) {
        const int idx = t + 512 * it;          // 1024 odd slots = (e3, k)
        const int e3 = idx >> 8, k = idx & 255;
        const int g = 2 * k + 1;
        const int b = min(max(k - 1, 0), 252);
        float4 W;
        if (k == 0)        W = make_float4( 0.3125f,  0.9375f, -0.3125f,  0.0625f);
        else if (k == 254) W = make_float4( 0.0625f, -0.3125f,  0.9375f,  0.3125f);
        else if (k == 255) W = make_float4(-0.3125f,  1.3125f, -2.1875f,  2.1875f);
        else               W = make_float4(-0.0625f,  0.5625f,  0.5625f, -0.0625f);
        fine[e3][g] = W.x * fine[e3][2 * b]     + W.y * fine[e3][2 * b + 2]
                    + W.z * fine[e3][2 * b + 4] + W.w * fine[e3][2 * b + 6];
    }
    __syncthreads();

    // ---- pairwise |diff| summed over g ----
    {
        const float r0 = fine[0][t], r1 = fine[1][t], r2 = fine[2][t], r3 = fine[3][t];
        float pr[6];
        pr[0] = fabsf(r0 - r1);
        pr[1] = fabsf(r0 - r2);
        pr[2] = fabsf(r0 - r3);
        pr[3] = fabsf(r1 - r2);
        pr[4] = fabsf(r1 - r3);
        pr[5] = fabsf(r2 - r3);
        #pragma unroll
        for (int pi = 0; pi < 6; ++pi) {
            float v = pr[pi];
            #pragma unroll
            for (int off = 32; off >= 1; off >>= 1) v += __shfl_xor(v, off, 64);
            if ((t & 63) == 0) wred[t >> 6][pi] = v;
        }
    }
    __syncthreads();
    if (t == 0) {
        const float scale = csh[3];
        float v[6];
        #pragma unroll
        for (int pi = 0; pi < 6; ++pi) {
            float sm = 0.f;
            #pragma unroll
            for (int w = 0; w < 8; ++w) sm += wred[w][pi];
            v[pi] = sm * scale;
        }
        float testv = v[0];
        #pragma unroll
        for (int pi = 1; pi < 6; ++pi) testv = fmaxf(testv, v[pi]);
        const float trainv = fmaxf(fmaxf(v[0], v[1]), v[3]);  // pairs (0,1),(0,2),(1,2)
        out[lf] = trainv;
        out[256 + lf] = testv;
        __threadfence();
        const int old = __hip_atomic_fetch_add(counter, 1, __ATOMIC_ACQ_REL,
                                               __HIP_MEMORY_SCOPE_AGENT);
        lastf = (old == 255);
    }
    __syncthreads();
    if (lastf && t < 64) {
        const int ff = t & 31;
        const int base = (t >= 32) ? 256 : 0;      // lanes 0-31: train, 32-63: test
        float m = -FLT_MAX;
        #pragma unroll
        for (int ll = 0; ll < 8; ++ll) {
            const float val = __hip_atomic_load(&out[base + ll * 32 + ff],
                                                __ATOMIC_RELAXED, __HIP_MEMORY_SCOPE_AGENT);
            m = fmaxf(m, val);
        }
        #pragma unroll
        for (int off = 16; off >= 1; off >>= 1) m += __shfl_xor(m, off, 32);
        if (ff == 0) out[512 + (base ? 1 : 0)] = m * (1.0f / 32.0f);
    }
}

extern "C" void kernel_launch(void* const* d_in, const int* in_sizes, int n_in,
                              void* d_out, int out_size, void* d_ws, size_t ws_size,
                              hipStream_t stream) {
    (void)in_sizes; (void)n_in; (void)out_size; (void)ws_size;
    const float* matrix = (const float*)d_in[0];
    const float* params = (const float*)d_in[1];
    const int*   dlen   = (const int*)d_in[2];
    float* out = (float*)d_out;
    float* ws  = (float*)d_ws;
    float* PT   = ws + PT_OFF;
    float* sxg  = ws + SX_OFF;
    float* sxxg = ws + SXX_OFF;
    float* minp = ws + MIN_OFF;
    float* maxp = ws + MAX_OFF;
    int*   cnt  = (int*)(ws + CNT_OFF);

    hipLaunchKernelGGL(stage_prep, dim3(256), dim3(256), 0, stream,
                       matrix, params, PT, sxg, sxxg, minp, maxp, cnt);
    hipLaunchKernelGGL(stage_kde4, dim3(256), dim3(512), 0, stream,
                       PT, sxg, sxxg, minp, maxp, dlen, cnt, out);
}